// Round 7
// baseline (124.240 us; speedup 1.0000x reference)
//
#include <hip/hip_runtime.h>
#include <stdint.h>

#define NND 2048   // nodes
#define NE  32     // embed
#define NH  4      // heads
#define HDIM 16    // head dim
#define NB  8      // batch

typedef __attribute__((ext_vector_type(4))) float f32x4;
typedef _Float16 f16x8 __attribute__((ext_vector_type(8)));
typedef __fp16 fp16x2 __attribute__((ext_vector_type(2)));

#define MFMAH(a,b,c) __builtin_amdgcn_mfma_f32_16x16x32_f16(a,b,c,0,0,0)

// ---------------- workspace layout (in float units) ----------------
static constexpr size_t OFF_QF    = 0;
static constexpr size_t OFF_KF    = 524288;
static constexpr size_t OFF_VT    = 1048576;
static constexpr size_t OFF_O     = 1572864;
static constexpr size_t OFF_R     = 2621440;
static constexpr size_t OFF_C     = 3670016;           // 65536
static constexpr size_t OFF_WQT   = 3866624;           // 524288
static constexpr size_t OFF_WBF   = 4390912;           // 32768
static constexpr size_t OFF_G     = 4423680;           // 512
static constexpr size_t OFF_MT    = 4424192;           // 131072
static constexpr size_t OFF_MM    = 4555264;           // 131072

// ---------------- helpers ----------------
__device__ __forceinline__ uint32_t f2h2(float a, float b) {
    union { _Float16 h[2]; uint32_t u; } x;
    x.h[0] = (_Float16)a; x.h[1] = (_Float16)b; return x.u;
}
__device__ __forceinline__ uint32_t pkh(float a, float b) {
    union { fp16x2 h; uint32_t u; } x;
    x.h = __builtin_amdgcn_cvt_pkrtz(a, b); return x.u;
}
union U4H8 { uint4 u; f16x8 h; };

#define ONE2 0x3C003C00u

// ---------------- QKV projection -> f16 layouts ----------------
__global__ __launch_bounds__(64) void qkv_kernel(
    const float* __restrict__ act, const float* __restrict__ embed,
    const float* __restrict__ Wq, const float* __restrict__ bq,
    const float* __restrict__ Wk, const float* __restrict__ bk,
    const float* __restrict__ Wv, const float* __restrict__ bv,
    ushort* __restrict__ Qf, ushort* __restrict__ Kf, ushort* __restrict__ Vt)
{
    const int blk = blockIdx.x;          // 1024 = 8 b * 128 chunks of 16 nodes
    const int b = blk >> 7, nc = blk & 127;
    const int j = threadIdx.x;           // channel 0..63

    float wq[NE], wk[NE], wv[NE];
    const float4* Wq4 = (const float4*)Wq;
    const float4* Wk4 = (const float4*)Wk;
    const float4* Wv4 = (const float4*)Wv;
#pragma unroll
    for (int t = 0; t < 8; ++t) {
        float4 a4 = Wq4[j * 8 + t];
        wq[4*t] = a4.x; wq[4*t+1] = a4.y; wq[4*t+2] = a4.z; wq[4*t+3] = a4.w;
        float4 b4 = Wk4[j * 8 + t];
        wk[4*t] = b4.x; wk[4*t+1] = b4.y; wk[4*t+2] = b4.z; wk[4*t+3] = b4.w;
        float4 c4 = Wv4[j * 8 + t];
        wv[4*t] = c4.x; wv[4*t+1] = c4.y; wv[4*t+2] = c4.z; wv[4*t+3] = c4.w;
    }
    const float bqj = bq[j], bkj = bk[j], bvj = bv[j];

    __shared__ float x[16][33];
    const float4* E4 = (const float4*)(embed + (size_t)nc * 16 * NE);
#pragma unroll
    for (int tt = 0; tt < 2; ++tt) {
        int t = tt * 64 + j;
        float4 e4 = E4[t];
        int row = t >> 3, col = (t & 7) * 4;
        float a = act[(size_t)b * NND + nc * 16 + row];
        x[row][col+0] = e4.x * a; x[row][col+1] = e4.y * a;
        x[row][col+2] = e4.z * a; x[row][col+3] = e4.w * a;
    }
    __syncthreads();

    __shared__ float qs[16][65], ks[16][65], vs[16][65];
    for (int ii = 0; ii < 16; ++ii) {
        float q = bqj, k = bkj, v = bvj;
#pragma unroll
        for (int e = 0; e < NE; ++e) {
            float xe = x[ii][e];
            q = fmaf(wq[e], xe, q);
            k = fmaf(wk[e], xe, k);
            v = fmaf(wv[e], xe, v);
        }
        qs[ii][j] = q * 0.25f;   // fold 1/sqrt(HD)
        ks[ii][j] = k;
        vs[ii][j] = v;
    }
    __syncthreads();

    const int c = j >> 4, ii = j & 15;
    {
        size_t row = ((size_t)(b*NH + c) << 11) + (nc << 4) + ii;
        uint32_t pk[8], pq[8];
#pragma unroll
        for (int t = 0; t < 8; ++t) {
            pk[t] = f2h2(ks[ii][c*16 + 2*t], ks[ii][c*16 + 2*t + 1]);
            pq[t] = f2h2(qs[ii][c*16 + 2*t], qs[ii][c*16 + 2*t + 1]);
        }
        uint4* dk = (uint4*)(Kf + row * 16);
        dk[0] = make_uint4(pk[0], pk[1], pk[2], pk[3]);
        dk[1] = make_uint4(pk[4], pk[5], pk[6], pk[7]);
        uint4* dq = (uint4*)(Qf + row * 16);
        dq[0] = make_uint4(pq[0], pq[1], pq[2], pq[3]);
        dq[1] = make_uint4(pq[4], pq[5], pq[6], pq[7]);
    }
    {
        uint32_t ph[8];
#pragma unroll
        for (int t = 0; t < 8; ++t)
            ph[t] = f2h2(vs[2*t][j], vs[2*t + 1][j]);
        size_t rowv = (((size_t)(b*NH + c) << 4) + ii) * 2048 + (nc << 4);
        uint4* dh = (uint4*)(Vt + rowv);
        dh[0] = make_uint4(ph[0], ph[1], ph[2], ph[3]);
        dh[1] = make_uint4(ph[4], ph[5], ph[6], ph[7]);
    }
}

// ---------------- adjacency -> both bit packings (64x64 tile, LDS transpose) ----------------
__global__ __launch_bounds__(256) void mask_kernel(
    const int* __restrict__ adj, uint32_t* __restrict__ maskT,
    uint32_t* __restrict__ maskM)
{
    const int nb = blockIdx.x >> 5, mb = blockIdx.x & 31;
    const int n0 = nb * 64, m0 = mb * 64;
    __shared__ unsigned char ld[64][68];
    const int t = threadIdx.x;
    const int r = t >> 2, cs = (t & 3) * 16;
    const int4* src = (const int4*)(adj + (size_t)(n0 + r) * 2048 + m0 + cs);
    int4 a0 = src[0], a1 = src[1], a2 = src[2], a3 = src[3];
    unsigned char* dst = &ld[r][cs];
    dst[0]=a0.x!=0; dst[1]=a0.y!=0; dst[2]=a0.z!=0; dst[3]=a0.w!=0;
    dst[4]=a1.x!=0; dst[5]=a1.y!=0; dst[6]=a1.z!=0; dst[7]=a1.w!=0;
    dst[8]=a2.x!=0; dst[9]=a2.y!=0; dst[10]=a2.z!=0; dst[11]=a2.w!=0;
    dst[12]=a3.x!=0; dst[13]=a3.y!=0; dst[14]=a3.z!=0; dst[15]=a3.w!=0;
    __syncthreads();
    const int wv = t >> 6, lane = t & 63;
#pragma unroll 4
    for (int q = 0; q < 16; ++q) {
        int rr = wv * 16 + q;
        unsigned long long bm = __ballot(ld[rr][lane] != 0);
        if (lane == 0) {
            maskT[(size_t)(m0 >> 5) * 2048 + n0 + rr]       = (uint32_t)bm;
            maskT[(size_t)((m0 >> 5) + 1) * 2048 + n0 + rr] = (uint32_t)(bm >> 32);
        }
    }
#pragma unroll 4
    for (int q = 0; q < 16; ++q) {
        int cc = wv * 16 + q;
        unsigned long long bm = __ballot(ld[lane][cc] != 0);
        if (lane == 0) {
            maskM[(size_t)(n0 >> 5) * 2048 + m0 + cc]       = (uint32_t)bm;
            maskM[(size_t)((n0 >> 5) + 1) * 2048 + m0 + cc] = (uint32_t)(bm >> 32);
        }
    }
}

// ---------------- fused attention: O (normalized) + WQT + wbf ----------------
// XCD-swizzled block mapping (4 bh per XCD -> K/V L2-resident) + explicit
// 2-stage register software pipeline (loads for iter u+1 issued before
// compute of iter u). LDS LUT expands mask bits; l via ones-A MFMAs.
__global__ __launch_bounds__(256) void attn_a_kernel(
    const ushort* __restrict__ Qf, const ushort* __restrict__ Kf,
    const ushort* __restrict__ Vt, const uint32_t* __restrict__ maskT,
    float* __restrict__ O, ushort* __restrict__ WQT, ushort* __restrict__ wbf)
{
    const int bid = blockIdx.x;
    const int bh   = ((bid & 7) << 2) | ((bid >> 3) & 3);   // XCD-local bh
    const int nblk = bid >> 5;
    const int wv = threadIdx.x >> 6, lane = threadIdx.x & 63;
    const int i = lane & 15, g = lane >> 4;
    const int g8 = g << 3;
    const int n = nblk * 64 + wv * 16 + i;
    const int fi = ((i >> 2) << 3) | (i & 3);
    const int koff = (g & 1) * 8;

    __shared__ uint2 LUT[16];
    __shared__ ushort twq[16][68];
    if (threadIdx.x < 16) {
        uint32_t v = threadIdx.x;
        LUT[v] = make_uint2(
            ((v & 1u) ? 0xFFFFu : 0u) | ((v & 2u) ? 0xFFFF0000u : 0u),
            ((v & 4u) ? 0xFFFFu : 0u) | ((v & 8u) ? 0xFFFF0000u : 0u));
    }
    __syncthreads();

    const ushort* Kb = Kf + (((size_t)bh << 11) << 4);
    const ushort* Vb = Vt + ((size_t)(bh * 16 + i) << 11);
    U4H8 qf; qf.u = make_uint4(0,0,0,0);
    if (g < 2) qf.u = *(const uint4*)(Qf + ((((size_t)bh << 11) + n) << 4) + koff);
    U4H8 ones; ones.u = make_uint4(ONE2, ONE2, ONE2, ONE2);
    f32x4 oa0 = {0.f,0.f,0.f,0.f}, oa1 = {0.f,0.f,0.f,0.f};
    f32x4 la0 = {0.f,0.f,0.f,0.f}, la1 = {0.f,0.f,0.f,0.f};
    const f32x4 zc = {0.f,0.f,0.f,0.f};
    const uint32_t* mrow = maskT + n;

#define LOADC(KA,KB,VH,MW,mbase) do { \
        KA.u = *(const uint4*)(Kb + ((size_t)((mbase) + fi) << 4) + koff); \
        KB.u = *(const uint4*)(Kb + ((size_t)((mbase) + fi + 4) << 4) + koff); \
        VH.u = *(const uint4*)(Vb + (mbase) + g8); \
        MW   = mrow[(size_t)((mbase) >> 5) << 11]; \
    } while (0)

#define COMPC(KA,KB,VH,MW,OACC,LACC) do { \
        f32x4 ca = MFMAH(KA.h, qf.h, zc); \
        f32x4 cb = MFMAH(KB.h, qf.h, zc); \
        const uint32_t mg = (MW) >> g8; \
        uint2 x01 = LUT[mg & 15u], x23 = LUT[(mg >> 4) & 15u]; \
        U4H8 mf, tf; \
        mf.u.x = x01.x & ONE2;  mf.u.y = x01.y & ONE2; \
        mf.u.z = x23.x & ONE2;  mf.u.w = x23.y & ONE2; \
        tf.u.x = pkh(ca[0], ca[1]) & x01.x; \
        tf.u.y = pkh(ca[2], ca[3]) & x01.y; \
        tf.u.z = pkh(cb[0], cb[1]) & x23.x; \
        tf.u.w = pkh(cb[2], cb[3]) & x23.y; \
        OACC = MFMAH(VH.h, mf.h, OACC); \
        OACC = MFMAH(VH.h, tf.h, OACC); \
        LACC = MFMAH(ones.h, mf.h, LACC); \
        LACC = MFMAH(ones.h, tf.h, LACC); \
    } while (0)

    U4H8 kaA0, kbA0, vhA0, kaB0, kbB0, vhB0;
    U4H8 kaA1, kbA1, vhA1, kaB1, kbB1, vhB1;
    uint32_t mwA0, mwB0, mwA1, mwB1;
    LOADC(kaA0, kbA0, vhA0, mwA0, 0);
    LOADC(kaB0, kbB0, vhB0, mwB0, 1024);

    for (int uu = 0; uu < 32; uu += 2) {
        const int m1 = (uu + 1) << 5;
        if (uu + 1 < 32) {
            LOADC(kaA1, kbA1, vhA1, mwA1, m1);
            LOADC(kaB1, kbB1, vhB1, mwB1, m1 + 1024);
        }
        COMPC(kaA0, kbA0, vhA0, mwA0, oa0, la0);
        COMPC(kaB0, kbB0, vhB0, mwB0, oa1, la1);
        const int m2 = (uu + 2) << 5;
        if (uu + 2 < 32) {
            LOADC(kaA0, kbA0, vhA0, mwA0, m2);
            LOADC(kaB0, kbB0, vhB0, mwB0, m2 + 1024);
        }
        COMPC(kaA1, kbA1, vhA1, mwA1, oa0, la0);
        COMPC(kaB1, kbB1, vhB1, mwB1, oa1, la1);
    }
#undef LOADC
#undef COMPC

    const float w = 1.0f / (la0[0] + la1[0]);   // full colsum in every lane
    f32x4 ov;
    ov[0] = (oa0[0] + oa1[0]) * w; ov[1] = (oa0[1] + oa1[1]) * w;
    ov[2] = (oa0[2] + oa1[2]) * w; ov[3] = (oa0[3] + oa1[3]) * w;
    *(f32x4*)(O + ((((size_t)bh << 11) + n) << 4) + (g << 2)) = ov;
    if (g == 0) {
        union { _Float16 h; ushort s; } cw; cw.h = (_Float16)(w * 256.0f);
        wbf[((size_t)bh << 11) + n] = cw.s;
    }
    // WQT = 256*w*q, transposed to [d][n] via LDS
    if (g < 2) {
        const float ws = w * 256.0f;
#pragma unroll
        for (int t = 0; t < 8; ++t) {
            union { _Float16 h; ushort s; } a;
            a.h = (_Float16)(ws * (float)qf.h[t]);
            twq[koff + t][wv * 16 + i] = a.s;
        }
    }
    __syncthreads();
    {
        const int d = threadIdx.x >> 4, seg = threadIdx.x & 15;
        uint2 v;
        v.x = (uint32_t)twq[d][seg*4]   | ((uint32_t)twq[d][seg*4+1] << 16);
        v.y = (uint32_t)twq[d][seg*4+2] | ((uint32_t)twq[d][seg*4+3] << 16);
        *(uint2*)(WQT + ((size_t)(bh * 16 + d) << 11) + nblk * 64 + seg * 4) = v;
    }
}

// ---------------- colsum: R = M^T (256 w q), c = M^T (256 w) via mask-MFMA ----------------
__global__ __launch_bounds__(256) void colsum_kernel(
    const ushort* __restrict__ WQT, const ushort* __restrict__ wbf,
    const uint32_t* __restrict__ maskM, float* __restrict__ R,
    float* __restrict__ cbuf)
{
    const int bid = blockIdx.x;
    const int bh  = ((bid & 7) << 2) | ((bid >> 3) & 3);   // XCD-local bh
    const int msb = bid >> 5;
    const int wv = threadIdx.x >> 6, lane = threadIdx.x & 63;
    const int i = lane & 15, g = lane >> 4;
    const int g8 = g << 3;
    const int mt0 = msb * 128 + wv * 16;
    const int mt1 = mt0 + 64;
    __shared__ uint2 LUT[16];
    __shared__ ushort wq[16][1040];
    if (threadIdx.x < 16) {
        uint32_t v = threadIdx.x;
        LUT[v] = make_uint2(
            ((v & 1u) ? 0xFFFFu : 0u) | ((v & 2u) ? 0xFFFF0000u : 0u),
            ((v & 4u) ? 0xFFFFu : 0u) | ((v & 8u) ? 0xFFFF0000u : 0u));
    }
    f32x4 aR0 = {0.f,0.f,0.f,0.f}, aR1 = {0.f,0.f,0.f,0.f};
    f32x4 aC0 = {0.f,0.f,0.f,0.f}, aC1 = {0.f,0.f,0.f,0.f};

    for (int half = 0; half < 2; ++half) {
        {   // stage WQT half-panel: [16 d][1024 n]
            int d = threadIdx.x >> 4, seg = (threadIdx.x & 15) * 64;
            const uint4* s = (const uint4*)(WQT + ((size_t)(bh * 16 + d) << 11)
                                            + half * 1024 + seg);
            uint4* dst = (uint4*)&wq[d][seg];
#pragma unroll
            for (int q = 0; q < 8; ++q) dst[q] = s[q];
        }
        __syncthreads();
        for (int uu = 0; uu < 32; ++uu) {
            const int u = half * 32 + uu;
            U4H8 b1; b1.u = *(const uint4*)&wq[i][uu * 32 + g * 8];
            U4H8 b2; b2.u = make_uint4(0,0,0,0);
            if (i == 0)
                b2.u = *(const uint4*)(wbf + ((size_t)bh << 11)
                                       + half * 1024 + uu * 32 + g * 8);
#pragma unroll
            for (int tt = 0; tt < 2; ++tt) {
                int mt = tt ? mt1 : mt0;
                uint32_t w0 = maskM[(size_t)u * 2048 + mt + i] >> g8;
                uint2 q01 = LUT[w0 & 15u], q23 = LUT[(w0 >> 4) & 15u];
                U4H8 af;
                af.u.x = q01.x & ONE2;
                af.u.y = q01.y & ONE2;
                af.u.z = q23.x & ONE2;
                af.u.w = q23.y & ONE2;
                if (tt) { aR1 = MFMAH(af.h, b1.h, aR1); aC1 = MFMAH(af.h, b2.h, aC1); }
                else    { aR0 = MFMAH(af.h, b1.h, aR0); aC0 = MFMAH(af.h, b2.h, aC0); }
            }
        }
        __syncthreads();
    }
#pragma unroll
    for (int r = 0; r < 4; ++r) {
        R[(((size_t)bh << 11) + mt0 + 4 * g + r) * 16 + i] = aR0[r];
        R[(((size_t)bh << 11) + mt1 + 4 * g + r) * 16 + i] = aR1[r];
    }
    if (i == 0) {
#pragma unroll
        for (int r = 0; r < 4; ++r) {
            cbuf[((size_t)bh << 11) + mt0 + 4 * g + r] = aC0[r];
            cbuf[((size_t)bh << 11) + mt1 + 4 * g + r] = aC1[r];
        }
    }
}

// ---------------- out-proj + ReLU + activation-weighted pooling ----------------
__global__ __launch_bounds__(256) void pool_kernel(
    const float* __restrict__ O, const float* __restrict__ act,
    const float* __restrict__ Wo, const float* __restrict__ bo,
    float* __restrict__ g)
{
    int b  = blockIdx.x >> 5;
    int nc = blockIdx.x & 31;        // 64-node chunk
    int lane = threadIdx.x & 63;     // output channel j
    int sw   = threadIdx.x >> 6;

    __shared__ float o_lds[64][65];
    __shared__ float w_lds[64][65];
    for (int t = threadIdx.x; t < 4096; t += 256) {
        int r = t >> 6, e = t & 63;
        w_lds[r][e] = Wo[t];
        int h = e >> 4, d = e & 15;
        size_t base = (((size_t)b * NH + h) * NND + nc * 64 + r) * HDIM + d;
        o_lds[r][e] = O[base];
    }
    __syncthreads();

    float boj = bo[lane];
    float acc = 0.f;
    for (int i = 0; i < 16; ++i) {
        int nn = sw * 16 + i;
        float d0 = 0.f, d1 = 0.f;
#pragma unroll
        for (int e = 0; e < 64; e += 2) {
            d0 = fmaf(o_lds[nn][e],   w_lds[lane][e],   d0);
            d1 = fmaf(o_lds[nn][e+1], w_lds[lane][e+1], d1);
        }
        float r = fmaxf(d0 + d1 + boj, 0.f);
        acc = fmaf(r, act[(size_t)b * NND + nc * 64 + nn], acc);
    }
    __shared__ float red[4][64];
    red[sw][lane] = acc;
    __syncthreads();
    if (sw == 0) {
        float sum = (red[0][lane] + red[1][lane]) + (red[2][lane] + red[3][lane]);
        atomicAdd(&g[b * 64 + lane], sum);
    }
}

// ---------------- finalize: blocks 0-63 node_attention, 64-71 LayerNorm ----------------
__global__ __launch_bounds__(256) void final_kernel(
    const float* __restrict__ act, const float* __restrict__ g,
    const float* __restrict__ cbuf, const float* __restrict__ R,
    const ushort* __restrict__ Kf, const float* __restrict__ gamma,
    const float* __restrict__ beta, float* __restrict__ out)
{
    const int blk = blockIdx.x;
    const int t = threadIdx.x;
    if (blk < 64) {
        const int b = blk >> 3, mc = blk & 7;
        const int m = mc * 256 + t;
        const float sc = 1.0f / (256.0f * NH * (float)NND);
        float cs = 0.f;
#pragma unroll
        for (int h = 0; h < NH; ++h) {
            size_t idx = (((size_t)(b * NH + h)) << 11) + m;
            cs += cbuf[idx];
            const f32x4* rr = (const f32x4*)(R + (idx << 4));
            const uint4* kk = (const uint4*)(Kf + (idx << 4));
            U4H8 k0, k1; k0.u = kk[0]; k1.u = kk[1];
            f32x4 r0 = rr[0], r1 = rr[1], r2 = rr[2], r3 = rr[3];
            cs += (float)k0.h[0]*r0[0] + (float)k0.h[1]*r0[1]
                + (float)k0.h[2]*r0[2] + (float)k0.h[3]*r0[3]
                + (float)k0.h[4]*r1[0] + (float)k0.h[5]*r1[1]
                + (float)k0.h[6]*r1[2] + (float)k0.h[7]*r1[3]
                + (float)k1.h[0]*r2[0] + (float)k1.h[1]*r2[1]
                + (float)k1.h[2]*r2[2] + (float)k1.h[3]*r2[3]
                + (float)k1.h[4]*r3[0] + (float)k1.h[5]*r3[1]
                + (float)k1.h[6]*r3[2] + (float)k1.h[7]*r3[3];
        }
        size_t oi = (size_t)b * NND + m;
        out[(size_t)NB * 64 + oi] = cs * sc * act[oi];
        return;
    }
    const int b = blk - 64;
    __shared__ float red[256];
    float s = 0.f;
    for (int n = t; n < NND; n += 256) s += act[(size_t)b * NND + n];
    red[t] = s;
    __syncthreads();
    for (int off = 128; off > 0; off >>= 1) {
        if (t < off) red[t] += red[t + off];
        __syncthreads();
    }
    float inv = 1.0f / fmaxf(red[0], 1.0f);
    __syncthreads();

    __shared__ float gv[64];
    __shared__ float st[2];
    if (t < 64) gv[t] = g[b * 64 + t] * inv;
    __syncthreads();
    if (t == 0) {
        float mu = 0.f;
        for (int jj = 0; jj < 64; ++jj) mu += gv[jj];
        mu *= (1.0f / 64.0f);
        float var = 0.f;
        for (int jj = 0; jj < 64; ++jj) { float d = gv[jj] - mu; var += d * d; }
        var *= (1.0f / 64.0f);
        st[0] = mu;
        st[1] = 1.0f / sqrtf(var + 1e-5f);
    }
    __syncthreads();
    if (t < 64) out[b * 64 + t] = (gv[t] - st[0]) * st[1] * gamma[t] + beta[t];
}

// ---------------- launch ----------------
extern "C" void kernel_launch(void* const* d_in, const int* in_sizes, int n_in,
                              void* d_out, int out_size, void* d_ws, size_t ws_size,
                              hipStream_t stream)
{
    const float* act   = (const float*)d_in[0];
    const int*   adj   = (const int*)d_in[1];
    const float* embed = (const float*)d_in[2];
    const float* Wq = (const float*)d_in[3];
    const float* bq = (const float*)d_in[4];
    const float* Wk = (const float*)d_in[5];
    const float* bk = (const float*)d_in[6];
    const float* Wv = (const float*)d_in[7];
    const float* bv = (const float*)d_in[8];
    const float* Wo = (const float*)d_in[9];
    const float* bo = (const float*)d_in[10];
    const float* gamma = (const float*)d_in[11];
    const float* beta  = (const float*)d_in[12];
    float* out = (float*)d_out;

    float* ws = (float*)d_ws;
    ushort* Qf  = (ushort*)(ws + OFF_QF);
    ushort* Kf  = (ushort*)(ws + OFF_KF);
    ushort* Vt  = (ushort*)(ws + OFF_VT);
    float*  O   = ws + OFF_O;
    float*  R   = ws + OFF_R;
    float*  cb  = ws + OFF_C;
    ushort* WQT = (ushort*)(ws + OFF_WQT);
    ushort* wbf = (ushort*)(ws + OFF_WBF);
    float*  gb  = ws + OFF_G;
    uint32_t* maskT = (uint32_t*)(ws + OFF_MT);
    uint32_t* maskM = (uint32_t*)(ws + OFF_MM);

    (void)hipMemsetAsync(ws + OFF_G, 0, 512 * sizeof(float), stream);

    qkv_kernel<<<NB * 128, 64, 0, stream>>>(act, embed, Wq, bq, Wk, bk, Wv, bv,
                                            Qf, Kf, Vt);
    mask_kernel<<<1024, 256, 0, stream>>>(adj, maskT, maskM);
    attn_a_kernel<<<1024, 256, 0, stream>>>(Qf, Kf, Vt, maskT, O, WQT, wbf);
    colsum_kernel<<<512, 256, 0, stream>>>(WQT, wbf, maskM, R, cb);
    pool_kernel<<<NB * 32, 256, 0, stream>>>(O, act, Wo, bo, gb);
    final_kernel<<<72, 256, 0, stream>>>(act, gb, cb, R, Kf, gamma, beta, out);
}

// Round 8
// 110.466 us; speedup vs baseline: 1.1247x; 1.1247x over previous
//
#include <hip/hip_runtime.h>
#include <stdint.h>

#define NND 2048   // nodes
#define NE  32     // embed
#define NH  4      // heads
#define HDIM 16    // head dim
#define NB  8      // batch

typedef __attribute__((ext_vector_type(4))) float f32x4;
typedef _Float16 f16x8 __attribute__((ext_vector_type(8)));
typedef __fp16 fp16x2 __attribute__((ext_vector_type(2)));

#define MFMAH(a,b,c) __builtin_amdgcn_mfma_f32_16x16x32_f16(a,b,c,0,0,0)

// ---------------- workspace layout (in float units) ----------------
static constexpr size_t OFF_QF    = 0;
static constexpr size_t OFF_KF    = 524288;
static constexpr size_t OFF_VT    = 1048576;
static constexpr size_t OFF_O     = 1572864;
static constexpr size_t OFF_R     = 2621440;
static constexpr size_t OFF_C     = 3670016;           // 65536
static constexpr size_t OFF_WQT   = 3866624;           // 524288
static constexpr size_t OFF_WBF   = 4390912;           // 32768
static constexpr size_t OFF_G     = 4423680;           // 512
static constexpr size_t OFF_MT2   = 4424192;           // maskT2: [32 nb][64 u][64 n] u32 = 131072 f
static constexpr size_t OFF_MM    = 4555264;           // maskM: 131072 f

// ---------------- helpers ----------------
__device__ __forceinline__ uint32_t f2h2(float a, float b) {
    union { _Float16 h[2]; uint32_t u; } x;
    x.h[0] = (_Float16)a; x.h[1] = (_Float16)b; return x.u;
}
__device__ __forceinline__ uint32_t pkh(float a, float b) {
    union { fp16x2 h; uint32_t u; } x;
    x.h = __builtin_amdgcn_cvt_pkrtz(a, b); return x.u;
}
union U4H8 { uint4 u; f16x8 h; };

#define ONE2 0x3C003C00u

// ---------------- QKV projection -> f16 layouts ----------------
__global__ __launch_bounds__(64) void qkv_kernel(
    const float* __restrict__ act, const float* __restrict__ embed,
    const float* __restrict__ Wq, const float* __restrict__ bq,
    const float* __restrict__ Wk, const float* __restrict__ bk,
    const float* __restrict__ Wv, const float* __restrict__ bv,
    ushort* __restrict__ Qf, ushort* __restrict__ Kf, ushort* __restrict__ Vt)
{
    const int blk = blockIdx.x;          // 1024 = 8 b * 128 chunks of 16 nodes
    const int b = blk >> 7, nc = blk & 127;
    const int j = threadIdx.x;           // channel 0..63

    float wq[NE], wk[NE], wv[NE];
    const float4* Wq4 = (const float4*)Wq;
    const float4* Wk4 = (const float4*)Wk;
    const float4* Wv4 = (const float4*)Wv;
#pragma unroll
    for (int t = 0; t < 8; ++t) {
        float4 a4 = Wq4[j * 8 + t];
        wq[4*t] = a4.x; wq[4*t+1] = a4.y; wq[4*t+2] = a4.z; wq[4*t+3] = a4.w;
        float4 b4 = Wk4[j * 8 + t];
        wk[4*t] = b4.x; wk[4*t+1] = b4.y; wk[4*t+2] = b4.z; wk[4*t+3] = b4.w;
        float4 c4 = Wv4[j * 8 + t];
        wv[4*t] = c4.x; wv[4*t+1] = c4.y; wv[4*t+2] = c4.z; wv[4*t+3] = c4.w;
    }
    const float bqj = bq[j], bkj = bk[j], bvj = bv[j];

    __shared__ float x[16][33];
    const float4* E4 = (const float4*)(embed + (size_t)nc * 16 * NE);
#pragma unroll
    for (int tt = 0; tt < 2; ++tt) {
        int t = tt * 64 + j;
        float4 e4 = E4[t];
        int row = t >> 3, col = (t & 7) * 4;
        float a = act[(size_t)b * NND + nc * 16 + row];
        x[row][col+0] = e4.x * a; x[row][col+1] = e4.y * a;
        x[row][col+2] = e4.z * a; x[row][col+3] = e4.w * a;
    }
    __syncthreads();

    __shared__ float qs[16][65], ks[16][65], vs[16][65];
    for (int ii = 0; ii < 16; ++ii) {
        float q = bqj, k = bkj, v = bvj;
#pragma unroll
        for (int e = 0; e < NE; ++e) {
            float xe = x[ii][e];
            q = fmaf(wq[e], xe, q);
            k = fmaf(wk[e], xe, k);
            v = fmaf(wv[e], xe, v);
        }
        qs[ii][j] = q * 0.25f;   // fold 1/sqrt(HD)
        ks[ii][j] = k;
        vs[ii][j] = v;
    }
    __syncthreads();

    const int c = j >> 4, ii = j & 15;
    {
        size_t row = ((size_t)(b*NH + c) << 11) + (nc << 4) + ii;
        uint32_t pk[8], pq[8];
#pragma unroll
        for (int t = 0; t < 8; ++t) {
            pk[t] = f2h2(ks[ii][c*16 + 2*t], ks[ii][c*16 + 2*t + 1]);
            pq[t] = f2h2(qs[ii][c*16 + 2*t], qs[ii][c*16 + 2*t + 1]);
        }
        uint4* dk = (uint4*)(Kf + row * 16);
        dk[0] = make_uint4(pk[0], pk[1], pk[2], pk[3]);
        dk[1] = make_uint4(pk[4], pk[5], pk[6], pk[7]);
        uint4* dq = (uint4*)(Qf + row * 16);
        dq[0] = make_uint4(pq[0], pq[1], pq[2], pq[3]);
        dq[1] = make_uint4(pq[4], pq[5], pq[6], pq[7]);
    }
    {
        uint32_t ph[8];
#pragma unroll
        for (int t = 0; t < 8; ++t)
            ph[t] = f2h2(vs[2*t][j], vs[2*t + 1][j]);
        size_t rowv = (((size_t)(b*NH + c) << 4) + ii) * 2048 + (nc << 4);
        uint4* dh = (uint4*)(Vt + rowv);
        dh[0] = make_uint4(ph[0], ph[1], ph[2], ph[3]);
        dh[1] = make_uint4(ph[4], ph[5], ph[6], ph[7]);
    }
}

// ---------------- adjacency -> maskT2 (attn) + maskM (colsum) ----------------
__global__ __launch_bounds__(256) void mask_kernel(
    const int* __restrict__ adj, uint32_t* __restrict__ maskT2,
    uint32_t* __restrict__ maskM)
{
    const int nb = blockIdx.x >> 5, mb = blockIdx.x & 31;
    const int n0 = nb * 64, m0 = mb * 64;
    __shared__ unsigned char ld[64][68];
    const int t = threadIdx.x;
    const int r = t >> 2, cs = (t & 3) * 16;
    const int4* src = (const int4*)(adj + (size_t)(n0 + r) * 2048 + m0 + cs);
    int4 a0 = src[0], a1 = src[1], a2 = src[2], a3 = src[3];
    unsigned char* dst = &ld[r][cs];
    dst[0]=a0.x!=0; dst[1]=a0.y!=0; dst[2]=a0.z!=0; dst[3]=a0.w!=0;
    dst[4]=a1.x!=0; dst[5]=a1.y!=0; dst[6]=a1.z!=0; dst[7]=a1.w!=0;
    dst[8]=a2.x!=0; dst[9]=a2.y!=0; dst[10]=a2.z!=0; dst[11]=a2.w!=0;
    dst[12]=a3.x!=0; dst[13]=a3.y!=0; dst[14]=a3.z!=0; dst[15]=a3.w!=0;
    __syncthreads();
    const int wv = t >> 6, lane = t & 63;
#pragma unroll 4
    for (int q = 0; q < 16; ++q) {
        int rr = wv * 16 + q;
        unsigned long long bm = __ballot(ld[rr][lane] != 0);
        if (lane == 0) {
            // maskT2[nb][u][nn]: bit b of word = adj[n0+rr][32u+b]
            maskT2[(size_t)nb * 4096 + (size_t)(m0 >> 5) * 64 + rr]       = (uint32_t)bm;
            maskT2[(size_t)nb * 4096 + (size_t)((m0 >> 5) + 1) * 64 + rr] = (uint32_t)(bm >> 32);
        }
    }
#pragma unroll 4
    for (int q = 0; q < 16; ++q) {
        int cc = wv * 16 + q;
        unsigned long long bm = __ballot(ld[lane][cc] != 0);
        if (lane == 0) {
            maskM[(size_t)(n0 >> 5) * 2048 + m0 + cc]       = (uint32_t)bm;
            maskM[(size_t)((n0 >> 5) + 1) * 2048 + m0 + cc] = (uint32_t)(bm >> 32);
        }
    }
}

// ---------------- fused attention: LDS-staged K/V/mask, reg double-buffer ----------------
// Wave roles per iter: w0 stages next K-chunk (1KB), w1 next V-chunk (1KB),
// w2 stages mask group (1KB / 4 iters). Issue-early / ds_write-late; one
// barrier per iter. Swizzled LDS placement (same involution both sides):
//   K unit (r,h)  at p = 2r + ((h + ((r>>3)&1)) & 1)
//   V unit (d,sg) at p = 4d + ((sg + ((d>>1)&3)) & 3)
__global__ __launch_bounds__(256) void attn_a_kernel(
    const ushort* __restrict__ Qf, const ushort* __restrict__ Kf,
    const ushort* __restrict__ Vt, const uint32_t* __restrict__ maskT2,
    float* __restrict__ O, ushort* __restrict__ WQT, ushort* __restrict__ wbf)
{
    const int bid = blockIdx.x;
    const int bh   = ((bid & 7) << 2) | ((bid >> 3) & 3);   // XCD-local bh
    const int nblk = bid >> 5;
    const int wv = threadIdx.x >> 6, lane = threadIdx.x & 63;
    const int i = lane & 15, g = lane >> 4;
    const int g8 = g << 3;
    const int n = nblk * 64 + wv * 16 + i;
    const int fi = ((i >> 2) << 3) | (i & 3);

    __shared__ ushort Kc[2][512];
    __shared__ ushort Vc[2][512];
    __shared__ uint32_t maskc[2][256];
    __shared__ uint2 LUT[16];
    __shared__ ushort twq[16][68];

    if (threadIdx.x < 16) {
        uint32_t v = threadIdx.x;
        LUT[v] = make_uint2(
            ((v & 1u) ? 0xFFFFu : 0u) | ((v & 2u) ? 0xFFFF0000u : 0u),
            ((v & 4u) ? 0xFFFFu : 0u) | ((v & 8u) ? 0xFFFF0000u : 0u));
    }

    const ushort* Kb = Kf + (((size_t)bh << 11) << 4);
    // staging source offsets (per-lane, inverse of LDS placement)
    const int sr = lane >> 1;
    const int sh = ((lane & 1) + ((lane >> 4) & 1)) & 1;
    const ushort* ksrc = Kb + (sr << 4) + (sh << 3);                       // + (m<<4)/iter
    const int sd = lane >> 2;
    const int sseg = ((lane & 3) - ((lane >> 3) & 3)) & 3;
    const ushort* vsrc = Vt + (((size_t)bh * 16 + sd) << 11) + (sseg << 3); // + m/iter
    const uint32_t* msrc = maskT2 + (size_t)nblk * 4096 + (lane << 2);      // + grp*256

    // compute-side LDS unit indices (precomputed)
    const int t0 = ((g & 1) + ((i >> 2) & 1)) & 1;
    const int pa = ((fi << 1) + t0) << 3;           // ushort index
    const int pb = (((fi + 4) << 1) + t0) << 3;
    const int pv = ((i << 2) + ((g + ((i >> 1) & 3)) & 3)) << 3;

    const int koff = (g & 1) * 8;
    U4H8 qf; qf.u = make_uint4(0,0,0,0);
    if (g < 2) qf.u = *(const uint4*)(Qf + ((((size_t)bh << 11) + n) << 4) + koff);
    U4H8 ones; ones.u = make_uint4(ONE2, ONE2, ONE2, ONE2);
    f32x4 oacc = {0.f,0.f,0.f,0.f}, la = {0.f,0.f,0.f,0.f};
    const f32x4 zc = {0.f,0.f,0.f,0.f};

    // prologue: stage chunk 0 + mask group 0
    uint4 sk = make_uint4(0,0,0,0), sv = make_uint4(0,0,0,0), sm = make_uint4(0,0,0,0);
    if (wv == 0) { sk = *(const uint4*)ksrc; *(uint4*)&Kc[0][lane * 8] = sk; }
    else if (wv == 1) { sv = *(const uint4*)vsrc; *(uint4*)&Vc[0][lane * 8] = sv; }
    else if (wv == 2) { sm = *(const uint4*)msrc; *(uint4*)&maskc[0][lane * 4] = sm; }
    __syncthreads();

    for (int u = 0; u < 64; ++u) {
        const int m1 = (u + 1) << 5;
        // issue next-chunk loads (latency hides under compute)
        if (u < 63) {
            if (wv == 0) sk = *(const uint4*)(ksrc + ((size_t)m1 << 4));
            else if (wv == 1) sv = *(const uint4*)(vsrc + m1);
            else if (wv == 2 && (u & 3) == 0 && ((u >> 2) + 1) < 16)
                sm = *(const uint4*)(msrc + ((u >> 2) + 1) * 256);
        }
        // compute chunk u from LDS
        const int buf = u & 1;
        U4H8 ka, kb, vh;
        ka.u = *(const uint4*)&Kc[buf][pa];
        kb.u = *(const uint4*)&Kc[buf][pb];
        vh.u = *(const uint4*)&Vc[buf][pv];
        const uint32_t mw = maskc[(u >> 2) & 1][((u & 3) << 6) + (wv << 4) + i];

        f32x4 ca = MFMAH(ka.h, qf.h, zc);   // rows m+8g+r
        f32x4 cb = MFMAH(kb.h, qf.h, zc);   // rows m+8g+4+r
        const uint32_t mg = mw >> g8;
        uint2 x01 = LUT[mg & 15u], x23 = LUT[(mg >> 4) & 15u];
        U4H8 mf, tf;
        mf.u.x = x01.x & ONE2;  mf.u.y = x01.y & ONE2;
        mf.u.z = x23.x & ONE2;  mf.u.w = x23.y & ONE2;
        tf.u.x = pkh(ca[0], ca[1]) & x01.x;
        tf.u.y = pkh(ca[2], ca[3]) & x01.y;
        tf.u.z = pkh(cb[0], cb[1]) & x23.x;
        tf.u.w = pkh(cb[2], cb[3]) & x23.y;
        oacc = MFMAH(vh.h, mf.h, oacc);
        oacc = MFMAH(vh.h, tf.h, oacc);
        la   = MFMAH(ones.h, mf.h, la);
        la   = MFMAH(ones.h, tf.h, la);

        // write staged data into the other buffer
        if (u < 63) {
            if (wv == 0) *(uint4*)&Kc[buf ^ 1][lane * 8] = sk;
            else if (wv == 1) *(uint4*)&Vc[buf ^ 1][lane * 8] = sv;
            else if (wv == 2 && (u & 3) == 0 && ((u >> 2) + 1) < 16)
                *(uint4*)&maskc[((u >> 2) + 1) & 1][lane * 4] = sm;
        }
        __syncthreads();
    }

    const float w = 1.0f / la[0];            // full colsum in every lane
    f32x4 ov;
    ov[0] = oacc[0] * w; ov[1] = oacc[1] * w;
    ov[2] = oacc[2] * w; ov[3] = oacc[3] * w;
    *(f32x4*)(O + ((((size_t)bh << 11) + n) << 4) + (g << 2)) = ov;
    if (g == 0) {
        union { _Float16 h; ushort s; } cw; cw.h = (_Float16)(w * 256.0f);
        wbf[((size_t)bh << 11) + n] = cw.s;
    }
    // WQT = 256*w*q, transposed to [d][n] via LDS
    if (g < 2) {
        const float ws = w * 256.0f;
#pragma unroll
        for (int t = 0; t < 8; ++t) {
            union { _Float16 h; ushort s; } a;
            a.h = (_Float16)(ws * (float)qf.h[t]);
            twq[koff + t][wv * 16 + i] = a.s;
        }
    }
    __syncthreads();
    {
        const int d = threadIdx.x >> 4, seg = threadIdx.x & 15;
        uint2 v;
        v.x = (uint32_t)twq[d][seg*4]   | ((uint32_t)twq[d][seg*4+1] << 16);
        v.y = (uint32_t)twq[d][seg*4+2] | ((uint32_t)twq[d][seg*4+3] << 16);
        *(uint2*)(WQT + ((size_t)(bh * 16 + d) << 11) + nblk * 64 + seg * 4) = v;
    }
}

// ---------------- colsum: R = M^T (256 w q), c = M^T (256 w) via mask-MFMA ----------------
__global__ __launch_bounds__(256) void colsum_kernel(
    const ushort* __restrict__ WQT, const ushort* __restrict__ wbf,
    const uint32_t* __restrict__ maskM, float* __restrict__ R,
    float* __restrict__ cbuf)
{
    const int bid = blockIdx.x;
    const int bh  = ((bid & 7) << 2) | ((bid >> 3) & 3);   // XCD-local bh
    const int msb = bid >> 5;
    const int wv = threadIdx.x >> 6, lane = threadIdx.x & 63;
    const int i = lane & 15, g = lane >> 4;
    const int g8 = g << 3;
    const int mt0 = msb * 128 + wv * 16;
    const int mt1 = mt0 + 64;
    __shared__ uint2 LUT[16];
    __shared__ ushort wq[16][1040];
    if (threadIdx.x < 16) {
        uint32_t v = threadIdx.x;
        LUT[v] = make_uint2(
            ((v & 1u) ? 0xFFFFu : 0u) | ((v & 2u) ? 0xFFFF0000u : 0u),
            ((v & 4u) ? 0xFFFFu : 0u) | ((v & 8u) ? 0xFFFF0000u : 0u));
    }
    f32x4 aR0 = {0.f,0.f,0.f,0.f}, aR1 = {0.f,0.f,0.f,0.f};
    f32x4 aC0 = {0.f,0.f,0.f,0.f}, aC1 = {0.f,0.f,0.f,0.f};

    for (int half = 0; half < 2; ++half) {
        {   // stage WQT half-panel: [16 d][1024 n]
            int d = threadIdx.x >> 4, seg = (threadIdx.x & 15) * 64;
            const uint4* s = (const uint4*)(WQT + ((size_t)(bh * 16 + d) << 11)
                                            + half * 1024 + seg);
            uint4* dst = (uint4*)&wq[d][seg];
#pragma unroll
            for (int q = 0; q < 8; ++q) dst[q] = s[q];
        }
        __syncthreads();
        for (int uu = 0; uu < 32; ++uu) {
            const int u = half * 32 + uu;
            U4H8 b1; b1.u = *(const uint4*)&wq[i][uu * 32 + g * 8];
            U4H8 b2; b2.u = make_uint4(0,0,0,0);
            if (i == 0)
                b2.u = *(const uint4*)(wbf + ((size_t)bh << 11)
                                       + half * 1024 + uu * 32 + g * 8);
#pragma unroll
            for (int tt = 0; tt < 2; ++tt) {
                int mt = tt ? mt1 : mt0;
                uint32_t w0 = maskM[(size_t)u * 2048 + mt + i] >> g8;
                uint2 q01 = LUT[w0 & 15u], q23 = LUT[(w0 >> 4) & 15u];
                U4H8 af;
                af.u.x = q01.x & ONE2;
                af.u.y = q01.y & ONE2;
                af.u.z = q23.x & ONE2;
                af.u.w = q23.y & ONE2;
                if (tt) { aR1 = MFMAH(af.h, b1.h, aR1); aC1 = MFMAH(af.h, b2.h, aC1); }
                else    { aR0 = MFMAH(af.h, b1.h, aR0); aC0 = MFMAH(af.h, b2.h, aC0); }
            }
        }
        __syncthreads();
    }
#pragma unroll
    for (int r = 0; r < 4; ++r) {
        R[(((size_t)bh << 11) + mt0 + 4 * g + r) * 16 + i] = aR0[r];
        R[(((size_t)bh << 11) + mt1 + 4 * g + r) * 16 + i] = aR1[r];
    }
    if (i == 0) {
#pragma unroll
        for (int r = 0; r < 4; ++r) {
            cbuf[((size_t)bh << 11) + mt0 + 4 * g + r] = aC0[r];
            cbuf[((size_t)bh << 11) + mt1 + 4 * g + r] = aC1[r];
        }
    }
}

// ---------------- out-proj + ReLU + activation-weighted pooling ----------------
__global__ __launch_bounds__(256) void pool_kernel(
    const float* __restrict__ O, const float* __restrict__ act,
    const float* __restrict__ Wo, const float* __restrict__ bo,
    float* __restrict__ g)
{
    int b  = blockIdx.x >> 5;
    int nc = blockIdx.x & 31;        // 64-node chunk
    int lane = threadIdx.x & 63;     // output channel j
    int sw   = threadIdx.x >> 6;

    __shared__ float o_lds[64][65];
    __shared__ float w_lds[64][65];
    for (int t = threadIdx.x; t < 4096; t += 256) {
        int r = t >> 6, e = t & 63;
        w_lds[r][e] = Wo[t];
        int h = e >> 4, d = e & 15;
        size_t base = (((size_t)b * NH + h) * NND + nc * 64 + r) * HDIM + d;
        o_lds[r][e] = O[base];
    }
    __syncthreads();

    float boj = bo[lane];
    float acc = 0.f;
    for (int i = 0; i < 16; ++i) {
        int nn = sw * 16 + i;
        float d0 = 0.f, d1 = 0.f;
#pragma unroll
        for (int e = 0; e < 64; e += 2) {
            d0 = fmaf(o_lds[nn][e],   w_lds[lane][e],   d0);
            d1 = fmaf(o_lds[nn][e+1], w_lds[lane][e+1], d1);
        }
        float r = fmaxf(d0 + d1 + boj, 0.f);
        acc = fmaf(r, act[(size_t)b * NND + nc * 64 + nn], acc);
    }
    __shared__ float red[4][64];
    red[sw][lane] = acc;
    __syncthreads();
    if (sw == 0) {
        float sum = (red[0][lane] + red[1][lane]) + (red[2][lane] + red[3][lane]);
        atomicAdd(&g[b * 64 + lane], sum);
    }
}

// ---------------- finalize: blocks 0-63 node_attention, 64-71 LayerNorm ----------------
__global__ __launch_bounds__(256) void final_kernel(
    const float* __restrict__ act, const float* __restrict__ g,
    const float* __restrict__ cbuf, const float* __restrict__ R,
    const ushort* __restrict__ Kf, const float* __restrict__ gamma,
    const float* __restrict__ beta, float* __restrict__ out)
{
    const int blk = blockIdx.x;
    const int t = threadIdx.x;
    if (blk < 64) {
        const int b = blk >> 3, mc = blk & 7;
        const int m = mc * 256 + t;
        const float sc = 1.0f / (256.0f * NH * (float)NND);
        float cs = 0.f;
#pragma unroll
        for (int h = 0; h < NH; ++h) {
            size_t idx = (((size_t)(b * NH + h)) << 11) + m;
            cs += cbuf[idx];
            const f32x4* rr = (const f32x4*)(R + (idx << 4));
            const uint4* kk = (const uint4*)(Kf + (idx << 4));
            U4H8 k0, k1; k0.u = kk[0]; k1.u = kk[1];
            f32x4 r0 = rr[0], r1 = rr[1], r2 = rr[2], r3 = rr[3];
            cs += (float)k0.h[0]*r0[0] + (float)k0.h[1]*r0[1]
                + (float)k0.h[2]*r0[2] + (float)k0.h[3]*r0[3]
                + (float)k0.h[4]*r1[0] + (float)k0.h[5]*r1[1]
                + (float)k0.h[6]*r1[2] + (float)k0.h[7]*r1[3]
                + (float)k1.h[0]*r2[0] + (float)k1.h[1]*r2[1]
                + (float)k1.h[2]*r2[2] + (float)k1.h[3]*r2[3]
                + (float)k1.h[4]*r3[0] + (float)k1.h[5]*r3[1]
                + (float)k1.h[6]*r3[2] + (float)k1.h[7]*r3[3];
        }
        size_t oi = (size_t)b * NND + m;
        out[(size_t)NB * 64 + oi] = cs * sc * act[oi];
        return;
    }
    const int b = blk - 64;
    __shared__ float red[256];
    float s = 0.f;
    for (int n = t; n < NND; n += 256) s += act[(size_t)b * NND + n];
    red[t] = s;
    __syncthreads();
    for (int off = 128; off > 0; off >>= 1) {
        if (t < off) red[t] += red[t + off];
        __syncthreads();
    }
    float inv = 1.0f / fmaxf(red[0], 1.0f);
    __syncthreads();

    __shared__ float gv[64];
    __shared__ float st[2];
    if (t < 64) gv[t] = g[b * 64 + t] * inv;
    __syncthreads();
    if (t == 0) {
        float mu = 0.f;
        for (int jj = 0; jj < 64; ++jj) mu += gv[jj];
        mu *= (1.0f / 64.0f);
        float var = 0.f;
        for (int jj = 0; jj < 64; ++jj) { float d = gv[jj] - mu; var += d * d; }
        var *= (1.0f / 64.0f);
        st[0] = mu;
        st[1] = 1.0f / sqrtf(var + 1e-5f);
    }
    __syncthreads();
    if (t < 64) out[b * 64 + t] = (gv[t] - st[0]) * st[1] * gamma[t] + beta[t];
}

// ---------------- launch ----------------
extern "C" void kernel_launch(void* const* d_in, const int* in_sizes, int n_in,
                              void* d_out, int out_size, void* d_ws, size_t ws_size,
                              hipStream_t stream)
{
    const float* act   = (const float*)d_in[0];
    const int*   adj   = (const int*)d_in[1];
    const float* embed = (const float*)d_in[2];
    const float* Wq = (const float*)d_in[3];
    const float* bq = (const float*)d_in[4];
    const float* Wk = (const float*)d_in[5];
    const float* bk = (const float*)d_in[6];
    const float* Wv = (const float*)d_in[7];
    const float* bv = (const float*)d_in[8];
    const float* Wo = (const float*)d_in[9];
    const float* bo = (const float*)d_in[10];
    const float* gamma = (const float*)d_in[11];
    const float* beta  = (const float*)d_in[12];
    float* out = (float*)d_out;

    float* ws = (float*)d_ws;
    ushort* Qf  = (ushort*)(ws + OFF_QF);
    ushort* Kf  = (ushort*)(ws + OFF_KF);
    ushort* Vt  = (ushort*)(ws + OFF_VT);
    float*  O   = ws + OFF_O;
    float*  R   = ws + OFF_R;
    float*  cb  = ws + OFF_C;
    ushort* WQT = (ushort*)(ws + OFF_WQT);
    ushort* wbf = (ushort*)(ws + OFF_WBF);
    float*  gb  = ws + OFF_G;
    uint32_t* maskT2 = (uint32_t*)(ws + OFF_MT2);
    uint32_t* maskM  = (uint32_t*)(ws + OFF_MM);

    (void)hipMemsetAsync(ws + OFF_G, 0, 512 * sizeof(float), stream);

    qkv_kernel<<<NB * 128, 64, 0, stream>>>(act, embed, Wq, bq, Wk, bk, Wv, bv,
                                            Qf, Kf, Vt);
    mask_kernel<<<1024, 256, 0, stream>>>(adj, maskT2, maskM);
    attn_a_kernel<<<1024, 256, 0, stream>>>(Qf, Kf, Vt, maskT2, O, WQT, wbf);
    colsum_kernel<<<512, 256, 0, stream>>>(WQT, wbf, maskM, R, cb);
    pool_kernel<<<NB * 32, 256, 0, stream>>>(O, act, Wo, bo, gb);
    final_kernel<<<72, 256, 0, stream>>>(act, gb, cb, R, Kf, gamma, beta, out);
}

// Round 9
// 106.643 us; speedup vs baseline: 1.1650x; 1.0358x over previous
//
#include <hip/hip_runtime.h>
#include <stdint.h>

#define NND 2048   // nodes
#define NE  32     // embed
#define NH  4      // heads
#define HDIM 16    // head dim
#define NB  8      // batch

typedef __attribute__((ext_vector_type(4))) float f32x4;
typedef _Float16 f16x8 __attribute__((ext_vector_type(8)));
typedef __fp16 fp16x2 __attribute__((ext_vector_type(2)));

#define MFMAH(a,b,c) __builtin_amdgcn_mfma_f32_16x16x32_f16(a,b,c,0,0,0)

// ---------------- workspace layout (in float units) ----------------
static constexpr size_t OFF_QF    = 0;
static constexpr size_t OFF_KF    = 524288;
static constexpr size_t OFF_VT    = 1048576;
static constexpr size_t OFF_O     = 1572864;
static constexpr size_t OFF_R     = 2621440;
static constexpr size_t OFF_C     = 3670016;           // 65536
static constexpr size_t OFF_WQT   = 3866624;           // 524288
static constexpr size_t OFF_WBF   = 4390912;           // 32768
static constexpr size_t OFF_MT2   = 4424192;           // maskT2: [32 nb][64 u][64 n] u32 = 131072 f
static constexpr size_t OFF_MM    = 4555264;           // maskM: 131072 f
static constexpr size_t OFF_GP    = 4686336;           // gpart: [8 b][32 nc][64] = 16384 f

// ---------------- helpers ----------------
__device__ __forceinline__ uint32_t f2h2(float a, float b) {
    union { _Float16 h[2]; uint32_t u; } x;
    x.h[0] = (_Float16)a; x.h[1] = (_Float16)b; return x.u;
}
__device__ __forceinline__ uint32_t pkh(float a, float b) {
    union { fp16x2 h; uint32_t u; } x;
    x.h = __builtin_amdgcn_cvt_pkrtz(a, b); return x.u;
}
union U4H8 { uint4 u; f16x8 h; };

#define ONE2 0x3C003C00u

// ---------------- QKV projection -> f16 layouts ----------------
__global__ __launch_bounds__(64) void qkv_kernel(
    const float* __restrict__ act, const float* __restrict__ embed,
    const float* __restrict__ Wq, const float* __restrict__ bq,
    const float* __restrict__ Wk, const float* __restrict__ bk,
    const float* __restrict__ Wv, const float* __restrict__ bv,
    ushort* __restrict__ Qf, ushort* __restrict__ Kf, ushort* __restrict__ Vt)
{
    const int blk = blockIdx.x;          // 1024 = 8 b * 128 chunks of 16 nodes
    const int b = blk >> 7, nc = blk & 127;
    const int j = threadIdx.x;           // channel 0..63

    float wq[NE], wk[NE], wv[NE];
    const float4* Wq4 = (const float4*)Wq;
    const float4* Wk4 = (const float4*)Wk;
    const float4* Wv4 = (const float4*)Wv;
#pragma unroll
    for (int t = 0; t < 8; ++t) {
        float4 a4 = Wq4[j * 8 + t];
        wq[4*t] = a4.x; wq[4*t+1] = a4.y; wq[4*t+2] = a4.z; wq[4*t+3] = a4.w;
        float4 b4 = Wk4[j * 8 + t];
        wk[4*t] = b4.x; wk[4*t+1] = b4.y; wk[4*t+2] = b4.z; wk[4*t+3] = b4.w;
        float4 c4 = Wv4[j * 8 + t];
        wv[4*t] = c4.x; wv[4*t+1] = c4.y; wv[4*t+2] = c4.z; wv[4*t+3] = c4.w;
    }
    const float bqj = bq[j], bkj = bk[j], bvj = bv[j];

    __shared__ float x[16][33];
    const float4* E4 = (const float4*)(embed + (size_t)nc * 16 * NE);
#pragma unroll
    for (int tt = 0; tt < 2; ++tt) {
        int t = tt * 64 + j;
        float4 e4 = E4[t];
        int row = t >> 3, col = (t & 7) * 4;
        float a = act[(size_t)b * NND + nc * 16 + row];
        x[row][col+0] = e4.x * a; x[row][col+1] = e4.y * a;
        x[row][col+2] = e4.z * a; x[row][col+3] = e4.w * a;
    }
    __syncthreads();

    __shared__ float qs[16][65], ks[16][65], vs[16][65];
    for (int ii = 0; ii < 16; ++ii) {
        float q = bqj, k = bkj, v = bvj;
#pragma unroll
        for (int e = 0; e < NE; ++e) {
            float xe = x[ii][e];
            q = fmaf(wq[e], xe, q);
            k = fmaf(wk[e], xe, k);
            v = fmaf(wv[e], xe, v);
        }
        qs[ii][j] = q * 0.25f;   // fold 1/sqrt(HD)
        ks[ii][j] = k;
        vs[ii][j] = v;
    }
    __syncthreads();

    const int c = j >> 4, ii = j & 15;
    {
        size_t row = ((size_t)(b*NH + c) << 11) + (nc << 4) + ii;
        uint32_t pk[8], pq[8];
#pragma unroll
        for (int t = 0; t < 8; ++t) {
            pk[t] = f2h2(ks[ii][c*16 + 2*t], ks[ii][c*16 + 2*t + 1]);
            pq[t] = f2h2(qs[ii][c*16 + 2*t], qs[ii][c*16 + 2*t + 1]);
        }
        uint4* dk = (uint4*)(Kf + row * 16);
        dk[0] = make_uint4(pk[0], pk[1], pk[2], pk[3]);
        dk[1] = make_uint4(pk[4], pk[5], pk[6], pk[7]);
        uint4* dq = (uint4*)(Qf + row * 16);
        dq[0] = make_uint4(pq[0], pq[1], pq[2], pq[3]);
        dq[1] = make_uint4(pq[4], pq[5], pq[6], pq[7]);
    }
    {
        uint32_t ph[8];
#pragma unroll
        for (int t = 0; t < 8; ++t)
            ph[t] = f2h2(vs[2*t][j], vs[2*t + 1][j]);
        size_t rowv = (((size_t)(b*NH + c) << 4) + ii) * 2048 + (nc << 4);
        uint4* dh = (uint4*)(Vt + rowv);
        dh[0] = make_uint4(ph[0], ph[1], ph[2], ph[3]);
        dh[1] = make_uint4(ph[4], ph[5], ph[6], ph[7]);
    }
}

// ---------------- adjacency -> maskT2 (attn) + maskM (colsum) ----------------
__global__ __launch_bounds__(256) void mask_kernel(
    const int* __restrict__ adj, uint32_t* __restrict__ maskT2,
    uint32_t* __restrict__ maskM)
{
    const int nb = blockIdx.x >> 5, mb = blockIdx.x & 31;
    const int n0 = nb * 64, m0 = mb * 64;
    __shared__ unsigned char ld[64][68];
    const int t = threadIdx.x;
    const int r = t >> 2, cs = (t & 3) * 16;
    const int4* src = (const int4*)(adj + (size_t)(n0 + r) * 2048 + m0 + cs);
    int4 a0 = src[0], a1 = src[1], a2 = src[2], a3 = src[3];
    unsigned char* dst = &ld[r][cs];
    dst[0]=a0.x!=0; dst[1]=a0.y!=0; dst[2]=a0.z!=0; dst[3]=a0.w!=0;
    dst[4]=a1.x!=0; dst[5]=a1.y!=0; dst[6]=a1.z!=0; dst[7]=a1.w!=0;
    dst[8]=a2.x!=0; dst[9]=a2.y!=0; dst[10]=a2.z!=0; dst[11]=a2.w!=0;
    dst[12]=a3.x!=0; dst[13]=a3.y!=0; dst[14]=a3.z!=0; dst[15]=a3.w!=0;
    __syncthreads();
    const int wv = t >> 6, lane = t & 63;
#pragma unroll 4
    for (int q = 0; q < 16; ++q) {
        int rr = wv * 16 + q;
        unsigned long long bm = __ballot(ld[rr][lane] != 0);
        if (lane == 0) {
            maskT2[(size_t)nb * 4096 + (size_t)(m0 >> 5) * 64 + rr]       = (uint32_t)bm;
            maskT2[(size_t)nb * 4096 + (size_t)((m0 >> 5) + 1) * 64 + rr] = (uint32_t)(bm >> 32);
        }
    }
#pragma unroll 4
    for (int q = 0; q < 16; ++q) {
        int cc = wv * 16 + q;
        unsigned long long bm = __ballot(ld[lane][cc] != 0);
        if (lane == 0) {
            maskM[(size_t)(n0 >> 5) * 2048 + m0 + cc]       = (uint32_t)bm;
            maskM[(size_t)((n0 >> 5) + 1) * 2048 + m0 + cc] = (uint32_t)(bm >> 32);
        }
    }
}

// ---------------- fused attention: group-of-4 LDS staging, double-buffered ----------------
// Per group (128 m): all 256 threads cooperatively stage K (4KB, linear),
// V (4KB, row-padded to 136 ushorts), mask (1KB). Loads for group g+1 issue
// BEFORE the 4-chunk compute of group g (~800cy) -> latency hidden; ds_writes
// after compute; ONE barrier per group (17 total vs 64).
__global__ __launch_bounds__(256) void attn_a_kernel(
    const ushort* __restrict__ Qf, const ushort* __restrict__ Kf,
    const ushort* __restrict__ Vt, const uint32_t* __restrict__ maskT2,
    float* __restrict__ O, ushort* __restrict__ WQT, ushort* __restrict__ wbf)
{
    const int bid = blockIdx.x;
    const int bh   = ((bid & 7) << 2) | ((bid >> 3) & 3);   // XCD-local bh
    const int nblk = bid >> 5;
    const int tt = threadIdx.x;
    const int wv = tt >> 6, lane = tt & 63;
    const int i = lane & 15, g = lane >> 4;
    const int g8 = g << 3;
    const int n = nblk * 64 + wv * 16 + i;
    const int fi = ((i >> 2) << 3) | (i & 3);
    const int koff = (g & 1) * 8;

    __shared__ ushort Kg[2][2048];       // 128 rows x 16 ushorts, linear
    __shared__ ushort Vg[2][2176];       // 16 d x 136 ushorts (128 m + 8 pad)
    __shared__ uint32_t Mg[2][256];      // 4 chunks x 64 n-words
    __shared__ uint2 LUT[16];
    __shared__ ushort twq[16][68];

    if (tt < 16) {
        uint32_t v = tt;
        LUT[v] = make_uint2(
            ((v & 1u) ? 0xFFFFu : 0u) | ((v & 2u) ? 0xFFFF0000u : 0u),
            ((v & 4u) ? 0xFFFFu : 0u) | ((v & 8u) ? 0xFFFF0000u : 0u));
    }

    const ushort* Kb = Kf + (((size_t)bh << 11) << 4);
    // staging sources (per thread): K fully linear; V 64B-segmented
    const ushort* ksrc = Kb + tt * 8;                                        // + m0*16/group
    const ushort* vsrc = Vt + (((size_t)bh * 16 + (tt & 15)) << 11) + ((tt >> 4) << 3); // + m0/group
    const uint32_t* msrc = maskT2 + (size_t)nblk * 4096;                     // + grp*256 + tt
    const int vdst = (tt & 15) * 136 + ((tt >> 4) << 3);

    U4H8 qf; qf.u = make_uint4(0,0,0,0);
    if (g < 2) qf.u = *(const uint4*)(Qf + ((((size_t)bh << 11) + n) << 4) + koff);
    U4H8 ones; ones.u = make_uint4(ONE2, ONE2, ONE2, ONE2);
    f32x4 oacc = {0.f,0.f,0.f,0.f}, la = {0.f,0.f,0.f,0.f};
    const f32x4 zc = {0.f,0.f,0.f,0.f};

    // prologue: stage group 0
    uint4 rk = *(const uint4*)ksrc;
    uint4 rv = *(const uint4*)vsrc;
    uint32_t rm = msrc[tt];
    *(uint4*)&Kg[0][tt * 8] = rk;
    *(uint4*)&Vg[0][vdst] = rv;
    Mg[0][tt] = rm;
    __syncthreads();

    for (int grp = 0; grp < 16; ++grp) {
        const int buf = grp & 1;
        if (grp < 15) {   // issue next-group loads first (hide under compute)
            const int m0 = (grp + 1) << 7;
            rk = *(const uint4*)(ksrc + ((size_t)m0 << 4));
            rv = *(const uint4*)(vsrc + m0);
            rm = msrc[(grp + 1) * 256 + tt];
        }
#pragma unroll
        for (int j = 0; j < 4; ++j) {
            U4H8 ka, kb, vh;
            ka.u = *(const uint4*)&Kg[buf][((j * 32 + fi) << 4) + koff];
            kb.u = *(const uint4*)&Kg[buf][((j * 32 + fi + 4) << 4) + koff];
            vh.u = *(const uint4*)&Vg[buf][i * 136 + j * 32 + g8];
            const uint32_t mw = Mg[buf][(j << 6) + (wv << 4) + i];

            f32x4 ca = MFMAH(ka.h, qf.h, zc);   // rows m+8g+r
            f32x4 cb = MFMAH(kb.h, qf.h, zc);   // rows m+8g+4+r
            const uint32_t mg = mw >> g8;
            uint2 x01 = LUT[mg & 15u], x23 = LUT[(mg >> 4) & 15u];
            U4H8 mf, tf;
            mf.u.x = x01.x & ONE2;  mf.u.y = x01.y & ONE2;
            mf.u.z = x23.x & ONE2;  mf.u.w = x23.y & ONE2;
            tf.u.x = pkh(ca[0], ca[1]) & x01.x;
            tf.u.y = pkh(ca[2], ca[3]) & x01.y;
            tf.u.z = pkh(cb[0], cb[1]) & x23.x;
            tf.u.w = pkh(cb[2], cb[3]) & x23.y;
            oacc = MFMAH(vh.h, mf.h, oacc);
            oacc = MFMAH(vh.h, tf.h, oacc);
            la   = MFMAH(ones.h, mf.h, la);
            la   = MFMAH(ones.h, tf.h, la);
        }
        if (grp < 15) {   // write staged data into the other buffer
            *(uint4*)&Kg[buf ^ 1][tt * 8] = rk;
            *(uint4*)&Vg[buf ^ 1][vdst] = rv;
            Mg[buf ^ 1][tt] = rm;
        }
        __syncthreads();
    }

    const float w = 1.0f / la[0];            // full colsum in every lane
    f32x4 ov;
    ov[0] = oacc[0] * w; ov[1] = oacc[1] * w;
    ov[2] = oacc[2] * w; ov[3] = oacc[3] * w;
    *(f32x4*)(O + ((((size_t)bh << 11) + n) << 4) + (g << 2)) = ov;
    if (g == 0) {
        union { _Float16 h; ushort s; } cw; cw.h = (_Float16)(w * 256.0f);
        wbf[((size_t)bh << 11) + n] = cw.s;
    }
    // WQT = 256*w*q, transposed to [d][n] via LDS
    if (g < 2) {
        const float ws = w * 256.0f;
#pragma unroll
        for (int t = 0; t < 8; ++t) {
            union { _Float16 h; ushort s; } a;
            a.h = (_Float16)(ws * (float)qf.h[t]);
            twq[koff + t][wv * 16 + i] = a.s;
        }
    }
    __syncthreads();
    {
        const int d = tt >> 4, seg = tt & 15;
        uint2 v;
        v.x = (uint32_t)twq[d][seg*4]   | ((uint32_t)twq[d][seg*4+1] << 16);
        v.y = (uint32_t)twq[d][seg*4+2] | ((uint32_t)twq[d][seg*4+3] << 16);
        *(uint2*)(WQT + ((size_t)(bh * 16 + d) << 11) + nblk * 64 + seg * 4) = v;
    }
}

// ---------------- colsum: R = M^T (256 w q), c = M^T (256 w) via mask-MFMA ----------------
__global__ __launch_bounds__(256) void colsum_kernel(
    const ushort* __restrict__ WQT, const ushort* __restrict__ wbf,
    const uint32_t* __restrict__ maskM, float* __restrict__ R,
    float* __restrict__ cbuf)
{
    const int bid = blockIdx.x;
    const int bh  = ((bid & 7) << 2) | ((bid >> 3) & 3);   // XCD-local bh
    const int msb = bid >> 5;
    const int wv = threadIdx.x >> 6, lane = threadIdx.x & 63;
    const int i = lane & 15, g = lane >> 4;
    const int g8 = g << 3;
    const int mt0 = msb * 128 + wv * 16;
    const int mt1 = mt0 + 64;
    __shared__ uint2 LUT[16];
    __shared__ ushort wq[16][1040];
    if (threadIdx.x < 16) {
        uint32_t v = threadIdx.x;
        LUT[v] = make_uint2(
            ((v & 1u) ? 0xFFFFu : 0u) | ((v & 2u) ? 0xFFFF0000u : 0u),
            ((v & 4u) ? 0xFFFFu : 0u) | ((v & 8u) ? 0xFFFF0000u : 0u));
    }
    f32x4 aR0 = {0.f,0.f,0.f,0.f}, aR1 = {0.f,0.f,0.f,0.f};
    f32x4 aC0 = {0.f,0.f,0.f,0.f}, aC1 = {0.f,0.f,0.f,0.f};

    for (int half = 0; half < 2; ++half) {
        {   // stage WQT half-panel: [16 d][1024 n]
            int d = threadIdx.x >> 4, seg = (threadIdx.x & 15) * 64;
            const uint4* s = (const uint4*)(WQT + ((size_t)(bh * 16 + d) << 11)
                                            + half * 1024 + seg);
            uint4* dst = (uint4*)&wq[d][seg];
#pragma unroll
            for (int q = 0; q < 8; ++q) dst[q] = s[q];
        }
        __syncthreads();
        for (int uu = 0; uu < 32; ++uu) {
            const int u = half * 32 + uu;
            U4H8 b1; b1.u = *(const uint4*)&wq[i][uu * 32 + g * 8];
            U4H8 b2; b2.u = make_uint4(0,0,0,0);
            if (i == 0)
                b2.u = *(const uint4*)(wbf + ((size_t)bh << 11)
                                       + half * 1024 + uu * 32 + g * 8);
#pragma unroll
            for (int tq = 0; tq < 2; ++tq) {
                int mt = tq ? mt1 : mt0;
                uint32_t w0 = maskM[(size_t)u * 2048 + mt + i] >> g8;
                uint2 q01 = LUT[w0 & 15u], q23 = LUT[(w0 >> 4) & 15u];
                U4H8 af;
                af.u.x = q01.x & ONE2;
                af.u.y = q01.y & ONE2;
                af.u.z = q23.x & ONE2;
                af.u.w = q23.y & ONE2;
                if (tq) { aR1 = MFMAH(af.h, b1.h, aR1); aC1 = MFMAH(af.h, b2.h, aC1); }
                else    { aR0 = MFMAH(af.h, b1.h, aR0); aC0 = MFMAH(af.h, b2.h, aC0); }
            }
        }
        __syncthreads();
    }
#pragma unroll
    for (int r = 0; r < 4; ++r) {
        R[(((size_t)bh << 11) + mt0 + 4 * g + r) * 16 + i] = aR0[r];
        R[(((size_t)bh << 11) + mt1 + 4 * g + r) * 16 + i] = aR1[r];
    }
    if (i == 0) {
#pragma unroll
        for (int r = 0; r < 4; ++r) {
            cbuf[((size_t)bh << 11) + mt0 + 4 * g + r] = aC0[r];
            cbuf[((size_t)bh << 11) + mt1 + 4 * g + r] = aC1[r];
        }
    }
}

// ---------------- out-proj + ReLU + pooling -> per-chunk partials ----------------
__global__ __launch_bounds__(256) void pool_kernel(
    const float* __restrict__ O, const float* __restrict__ act,
    const float* __restrict__ Wo, const float* __restrict__ bo,
    float* __restrict__ gpart)
{
    int b  = blockIdx.x >> 5;
    int nc = blockIdx.x & 31;        // 64-node chunk
    int lane = threadIdx.x & 63;     // output channel j
    int sw   = threadIdx.x >> 6;

    __shared__ float o_lds[64][65];
    __shared__ float w_lds[64][65];
    for (int t = threadIdx.x; t < 4096; t += 256) {
        int r = t >> 6, e = t & 63;
        w_lds[r][e] = Wo[t];
        int h = e >> 4, d = e & 15;
        size_t base = (((size_t)b * NH + h) * NND + nc * 64 + r) * HDIM + d;
        o_lds[r][e] = O[base];
    }
    __syncthreads();

    float boj = bo[lane];
    float acc = 0.f;
    for (int i = 0; i < 16; ++i) {
        int nn = sw * 16 + i;
        float d0 = 0.f, d1 = 0.f;
#pragma unroll
        for (int e = 0; e < 64; e += 2) {
            d0 = fmaf(o_lds[nn][e],   w_lds[lane][e],   d0);
            d1 = fmaf(o_lds[nn][e+1], w_lds[lane][e+1], d1);
        }
        float r = fmaxf(d0 + d1 + boj, 0.f);
        acc = fmaf(r, act[(size_t)b * NND + nc * 64 + nn], acc);
    }
    __shared__ float red[4][64];
    red[sw][lane] = acc;
    __syncthreads();
    if (sw == 0) {
        float sum = (red[0][lane] + red[1][lane]) + (red[2][lane] + red[3][lane]);
        gpart[((size_t)(b * 32 + nc)) * 64 + lane] = sum;
    }
}

// ---------------- finalize: blocks 0-63 node_attention, 64-71 LayerNorm ----------------
__global__ __launch_bounds__(256) void final_kernel(
    const float* __restrict__ act, const float* __restrict__ gpart,
    const float* __restrict__ cbuf, const float* __restrict__ R,
    const ushort* __restrict__ Kf, const float* __restrict__ gamma,
    const float* __restrict__ beta, float* __restrict__ out)
{
    const int blk = blockIdx.x;
    const int t = threadIdx.x;
    if (blk < 64) {
        const int b = blk >> 3, mc = blk & 7;
        const int m = mc * 256 + t;
        const float sc = 1.0f / (256.0f * NH * (float)NND);
        float cs = 0.f;
#pragma unroll
        for (int h = 0; h < NH; ++h) {
            size_t idx = (((size_t)(b * NH + h)) << 11) + m;
            cs += cbuf[idx];
            const f32x4* rr = (const f32x4*)(R + (idx << 4));
            const uint4* kk = (const uint4*)(Kf + (idx << 4));
            U4H8 k0, k1; k0.u = kk[0]; k1.u = kk[1];
            f32x4 r0 = rr[0], r1 = rr[1], r2 = rr[2], r3 = rr[3];
            cs += (float)k0.h[0]*r0[0] + (float)k0.h[1]*r0[1]
                + (float)k0.h[2]*r0[2] + (float)k0.h[3]*r0[3]
                + (float)k0.h[4]*r1[0] + (float)k0.h[5]*r1[1]
                + (float)k0.h[6]*r1[2] + (float)k0.h[7]*r1[3]
                + (float)k1.h[0]*r2[0] + (float)k1.h[1]*r2[1]
                + (float)k1.h[2]*r2[2] + (float)k1.h[3]*r2[3]
                + (float)k1.h[4]*r3[0] + (float)k1.h[5]*r3[1]
                + (float)k1.h[6]*r3[2] + (float)k1.h[7]*r3[3];
        }
        size_t oi = (size_t)b * NND + m;
        out[(size_t)NB * 64 + oi] = cs * sc * act[oi];
        return;
    }
    const int b = blk - 64;
    __shared__ float red[256];
    float s = 0.f;
    for (int n = t; n < NND; n += 256) s += act[(size_t)b * NND + n];
    red[t] = s;
    __syncthreads();
    for (int off = 128; off > 0; off >>= 1) {
        if (t < off) red[t] += red[t + off];
        __syncthreads();
    }
    float inv = 1.0f / fmaxf(red[0], 1.0f);
    __syncthreads();

    __shared__ float gv[64];
    __shared__ float st[2];
    if (t < 64) {
        float sgl = 0.f;
        const float* gp = gpart + (size_t)b * 32 * 64 + t;
#pragma unroll
        for (int c = 0; c < 32; ++c) sgl += gp[c * 64];
        gv[t] = sgl * inv;
    }
    __syncthreads();
    if (t == 0) {
        float mu = 0.f;
        for (int jj = 0; jj < 64; ++jj) mu += gv[jj];
        mu *= (1.0f / 64.0f);
        float var = 0.f;
        for (int jj = 0; jj < 64; ++jj) { float d = gv[jj] - mu; var += d * d; }
        var *= (1.0f / 64.0f);
        st[0] = mu;
        st[1] = 1.0f / sqrtf(var + 1e-5f);
    }
    __syncthreads();
    if (t < 64) out[b * 64 + t] = (gv[t] - st[0]) * st[1] * gamma[t] + beta[t];
}

// ---------------- launch ----------------
extern "C" void kernel_launch(void* const* d_in, const int* in_sizes, int n_in,
                              void* d_out, int out_size, void* d_ws, size_t ws_size,
                              hipStream_t stream)
{
    const float* act   = (const float*)d_in[0];
    const int*   adj   = (const int*)d_in[1];
    const float* embed = (const float*)d_in[2];
    const float* Wq = (const float*)d_in[3];
    const float* bq = (const float*)d_in[4];
    const float* Wk = (const float*)d_in[5];
    const float* bk = (const float*)d_in[6];
    const float* Wv = (const float*)d_in[7];
    const float* bv = (const float*)d_in[8];
    const float* Wo = (const float*)d_in[9];
    const float* bo = (const float*)d_in[10];
    const float* gamma = (const float*)d_in[11];
    const float* beta  = (const float*)d_in[12];
    float* out = (float*)d_out;

    float* ws = (float*)d_ws;
    ushort* Qf  = (ushort*)(ws + OFF_QF);
    ushort* Kf  = (ushort*)(ws + OFF_KF);
    ushort* Vt  = (ushort*)(ws + OFF_VT);
    float*  O   = ws + OFF_O;
    float*  R   = ws + OFF_R;
    float*  cb  = ws + OFF_C;
    ushort* WQT = (ushort*)(ws + OFF_WQT);
    ushort* wbf = (ushort*)(ws + OFF_WBF);
    float*  gp  = ws + OFF_GP;
    uint32_t* maskT2 = (uint32_t*)(ws + OFF_MT2);
    uint32_t* maskM  = (uint32_t*)(ws + OFF_MM);

    qkv_kernel<<<NB * 128, 64, 0, stream>>>(act, embed, Wq, bq, Wk, bk, Wv, bv,
                                            Qf, Kf, Vt);
    mask_kernel<<<1024, 256, 0, stream>>>(adj, maskT2, maskM);
    attn_a_kernel<<<1024, 256, 0, stream>>>(Qf, Kf, Vt, maskT2, O, WQT, wbf);
    colsum_kernel<<<512, 256, 0, stream>>>(WQT, wbf, maskM, R, cb);
    pool_kernel<<<NB * 32, 256, 0, stream>>>(O, act, Wo, bo, gp);
    final_kernel<<<72, 256, 0, stream>>>(act, gp, cb, R, Kf, gamma, beta, out);
}